// Round 11
// baseline (165.401 us; speedup 1.0000x reference)
//
#include <hip/hip_runtime.h>
#include <hip/hip_bf16.h>
#include <stdint.h>

typedef __attribute__((ext_vector_type(8))) short  short8;   // 8 bf16 (4 VGPR) MFMA A/B frag
typedef __attribute__((ext_vector_type(4))) short  short4v;
typedef __attribute__((ext_vector_type(4))) float  float4v;  // MFMA C/D frag

#define MFMA16(a, b, c) __builtin_amdgcn_mfma_f32_16x16x32_bf16((a), (b), (c), 0, 0, 0)

#define S_LEN  4096
#define NBATCH 4
#define EMB    1024
#define DD     64
#define NROWS  (NBATCH * S_LEN)  // 16384
#define SCL2   0.1803368801111204f  // (1/sqrt(64)) * log2(e), folded into Wq at wcvt

#define AS1 const __attribute__((address_space(1))) unsigned int*
#define AS3 __attribute__((address_space(3))) unsigned int*

static __device__ __forceinline__ short f2bf(float f) {
  uint32_t u = __float_as_uint(f);
  return (short)((u + 0x7FFFu + ((u >> 16) & 1u)) >> 16);
}
static __device__ __forceinline__ unsigned pk2(float a, float b) {
  union { __hip_bfloat162 h; unsigned u; } z;
  z.h = __float22bfloat162_rn(make_float2(a, b));
  return z.u;
}
static __device__ __forceinline__ short8 cvt8(float4v a, float4v b) {
  union { unsigned u[4]; short8 s; } z;
  z.u[0] = pk2(a[0], a[1]); z.u[1] = pk2(a[2], a[3]);
  z.u[2] = pk2(b[0], b[1]); z.u[3] = pk2(b[2], b[3]);
  return z.s;
}

// ============ Kernel 0: W fp32 -> bf16, reordered into 32-k panels ============
__global__ void wcvt_kernel(const float* __restrict__ Wq, const float* __restrict__ Wk,
                            const float* __restrict__ Wv, short* __restrict__ Wb2) {
  const int t   = blockIdx.x * 256 + threadIdx.x;
  const int row = t >> 7;
  const int k   = (t & 127) * 8;
  const float* src = (row < 64) ? (Wq + (size_t)row * EMB)
                   : (row < 128) ? (Wk + (size_t)(row - 64) * EMB)
                                 : (Wv + (size_t)(row - 128) * EMB);
  const float sc = (row < 64) ? SCL2 : 1.0f;
  float4v a = *(const float4v*)(src + k);
  float4v b = *(const float4v*)(src + k + 4);
#pragma unroll
  for (int i = 0; i < 4; ++i) { a[i] *= sc; b[i] *= sc; }
  *(short8*)(Wb2 + (((k >> 5) * 192 + row) << 5) + (k & 31)) = cvt8(a, b);
}

// ======================= Kernel 1: QKV projection GEMM =======================
// (unchanged -- m97 barrier double-buffer, the proven pattern)
__global__ __launch_bounds__(256, 2) void qkv_kernel(
    const float* __restrict__ x, const short* __restrict__ Wb2,
    short* __restrict__ Qb, short* __restrict__ Kb, short* __restrict__ Vt) {
  __shared__ float As[2][2048];
  __shared__ short Bs[2][12288];

  const int tid  = threadIdx.x;
  const int w    = tid >> 6;
  const int lane = tid & 63;
  const int ln   = lane & 15;
  const int quad = lane >> 4;
  const int m0   = blockIdx.x * 32;
  const int wr   = w & 1;
  const int wc   = w >> 1;

  const int tA0 = 2 * w, tA1 = 2 * w + 1;
  const float* xA0 = x + (size_t)(m0 + ((tA0 >> 2) << 4) + (lane >> 2)) * EMB
                       + ((tA0 & 3) * 4 + (lane & 3)) * 4;
  const float* xA1 = x + (size_t)(m0 + ((tA1 >> 2) << 4) + (lane >> 2)) * EMB
                       + ((tA1 & 3) * 4 + (lane & 3)) * 4;
  const short* wB = Wb2 + (size_t)(6 * w) * 512 + lane * 8;

#define STAGE(S, BUF) do {                                                      \
    __builtin_amdgcn_global_load_lds((AS1)(xA0 + (S) * 64),                     \
        (AS3)&As[BUF][tA0 * 256], 16, 0, 0);                                    \
    __builtin_amdgcn_global_load_lds((AS1)(xA1 + (S) * 64),                     \
        (AS3)&As[BUF][tA1 * 256], 16, 0, 0);                                    \
    _Pragma("unroll")                                                           \
    for (int j = 0; j < 6; ++j)                                                 \
      __builtin_amdgcn_global_load_lds((AS1)(wB + (size_t)(S) * 12288 + j * 512),\
          (AS3)&Bs[BUF][(6 * w + j) * 512], 16, 0, 0);                          \
  } while (0)

  const float4v zz = {0.f, 0.f, 0.f, 0.f};
  float4v acc[6] = {zz, zz, zz, zz, zz, zz};

  STAGE(0, 0);
  int buf = 0;
  for (int s = 0; s < 16; ++s) {
    __syncthreads();
    if (s + 1 < 16) STAGE(s + 1, buf ^ 1);
    short8 aF[2];
#pragma unroll
    for (int h = 0; h < 2; ++h) {
      const int ai = (wr * 4 + 2 * h + (quad >> 1)) * 256 + (ln * 4 + (quad & 1) * 2) * 4;
      const float4v lo = *(const float4v*)&As[buf][ai];
      const float4v hi = *(const float4v*)&As[buf][ai + 4];
      aF[h] = cvt8(lo, hi);
    }
#pragma unroll
    for (int f = 0; f < 6; ++f) {
      const int cf = wc * 6 + f;
      const short8 b0 = *(const short8*)&Bs[buf][(cf * 16 + ln) * 32 + quad * 8];
      const short8 b1 = *(const short8*)&Bs[buf][6144 + (cf * 16 + ln) * 32 + quad * 8];
      if (wc == 0 || f < 2) {
        acc[f] = MFMA16(aF[0], b0, acc[f]);
        acc[f] = MFMA16(aF[1], b1, acc[f]);
      } else {
        acc[f] = MFMA16(b0, aF[0], acc[f]);
        acc[f] = MFMA16(b1, aF[1], acc[f]);
      }
    }
    buf ^= 1;
  }
#undef STAGE

  const int b  = m0 >> 12;
  const int sb = m0 & (S_LEN - 1);
  if (wc == 0) {
#pragma unroll
    for (int f = 0; f < 6; ++f)
#pragma unroll
      for (int r = 0; r < 4; ++r) {
        const int row = m0 + wr * 16 + quad * 4 + r;
        if (f < 4) Qb[(size_t)row * DD + f * 16 + ln] = f2bf(acc[f][r]);
        else       Kb[(size_t)row * DD + (f - 4) * 16 + ln] = f2bf(acc[f][r]);
      }
  } else {
#pragma unroll
    for (int f = 0; f < 2; ++f)
#pragma unroll
      for (int r = 0; r < 4; ++r) {
        const int row = m0 + wr * 16 + quad * 4 + r;
        Kb[(size_t)row * DD + 32 + f * 16 + ln] = f2bf(acc[f][r]);
      }
#pragma unroll
    for (int f = 2; f < 6; ++f)
#pragma unroll
      for (int r = 0; r < 4; ++r) {
        const int d = (f - 2) * 16 + quad * 4 + r;
        Vt[((size_t)b * DD + d) * S_LEN + sb + wr * 16 + ln] = f2bf(acc[f][r]);
      }
  }
}

// ======================= Kernel 2: causal flash attention =======================
// Round 11: block-cooperative m97 barrier pattern (the only staging structure
// that ever worked here -- see qkv). 256 blocks x 512 thr (8 waves). Block =
// 32-row band pair (j, 127-j); per-pair kv-128 steps sum to a uniform 33.
// Per step: stage K(128x64)+V(64x128) = 32 KB into the SHARED double buffer
// (4 DMA instr/wave), one barrier, DMA(t+1) issued right after it. Wave =
// (q-half, kv-quarter): 8 MFMAs + 8 exps per step. XOR-swizzled DMA lane maps
// give 2-way (free) LDS banks on all frag reads. O/l combined once per phase
// through the drained K LDS.
__global__ __launch_bounds__(512, 1) void attn_kernel(
    const short* __restrict__ Qb, const short* __restrict__ Kb,
    const short* __restrict__ Vt, float* __restrict__ out) {
  __shared__ short Ks[2][8192];      // 32 KB: K tile 128 kv x 64 d, swizzled
  __shared__ short Vs[2][8192];      // 32 KB: V tile 64 d x 128 kv, swizzled
  __shared__ float pbuf[8][16 * 34]; // 17.4 KB per-wave P (16 q x 32 kv fp32)
  __shared__ float llds[8][16];

  const int tid  = threadIdx.x;
  const int w    = tid >> 6;
  const int lane = tid & 63;
  const int ln   = lane & 15;
  const int quad = lane >> 4;
  const int qh   = w & 1;   // q-half (16 rows)
  const int kh   = w >> 1;  // kv-quarter (32 of 128)
  const int g    = blockIdx.x;
  const int b    = g & 3;
  const int j    = g >> 2;  // 0..63 -> pair (j, 127-j)

  const short* Kbase = Kb + (size_t)b * S_LEN * DD;
  const short* Vbase = Vt + (size_t)b * DD * S_LEN;
  float* pw = &pbuf[w][0];
  const float4v zz = {0.f, 0.f, 0.f, 0.f};

  // ---- DMA lane maps (16B units expressed in shorts) ----
  // K slot t (8 rows x 64 d): lane i -> row 8t+(i>>3), chunk (i&7)^(i>>3)
  const int kT0 = 2 * w, kT1 = 2 * w + 1;
  const int kR0 = 8 * kT0 + (lane >> 3), kR1 = 8 * kT1 + (lane >> 3);
  const int kC  = ((lane & 7) ^ (lane >> 3)) * 8;
  // V slot u (4 d-rows x 128 kv): lane i -> row 4u+(i>>4),
  //   chunk (i&15)^(i>>4)^((u&1)*4)
  const int vU0 = 2 * w, vU1 = 2 * w + 1;
  const int vR0 = 4 * vU0 + (lane >> 4), vR1 = 4 * vU1 + (lane >> 4);
  const int vC0 = (((lane & 15) ^ (lane >> 4)) & 15) * 8;
  const int vC1 = ((((lane & 15) ^ (lane >> 4)) ^ 4) & 15) * 8;

#define KVSTAGE(KV0, BUF) do {                                                  \
    __builtin_amdgcn_global_load_lds((AS1)(Kbase + (size_t)((KV0) + kR0) * DD + kC), \
        (AS3)&Ks[BUF][kT0 * 512], 16, 0, 0);                                    \
    __builtin_amdgcn_global_load_lds((AS1)(Kbase + (size_t)((KV0) + kR1) * DD + kC), \
        (AS3)&Ks[BUF][kT1 * 512], 16, 0, 0);                                    \
    __builtin_amdgcn_global_load_lds((AS1)(Vbase + (KV0) + (size_t)vR0 * S_LEN + vC0), \
        (AS3)&Vs[BUF][vU0 * 512], 16, 0, 0);                                    \
    __builtin_amdgcn_global_load_lds((AS1)(Vbase + (KV0) + (size_t)vR1 * S_LEN + vC1), \
        (AS3)&Vs[BUF][vU1 * 512], 16, 0, 0);                                    \
  } while (0)

  for (int ph = 0; ph < 2; ++ph) {
    const int band = ph ? (127 - j) : j;
    const int qb   = band * 32;
    const int qg0  = b * S_LEN + qb;
    const int T    = (qb + 159) >> 7;  // ceil((qb+32)/128) kv-128 tiles

    short8 aQ[2];
#pragma unroll
    for (int h = 0; h < 2; ++h)
      aQ[h] = *(const short8*)(Qb + (size_t)(qg0 + qh * 16 + ln) * DD + h * 32 + quad * 8);

    float4v o[4] = {zz, zz, zz, zz};
    float lp[4]  = {0.f, 0.f, 0.f, 0.f};

    KVSTAGE(0, 0);
    for (int it = 0; it < T; ++it) {
      __syncthreads();                               // drains this buf's DMA
      if (it + 1 < T) KVSTAGE((it + 1) * 128, (it + 1) & 1);  // overlaps compute
      const int buf = it & 1;
      const int kv0 = it * 128;

      // K frags: row kh*32+ct*16+ln, d-half h (swizzle-matched addressing)
      short8 kf[2][2];
#pragma unroll
      for (int ct = 0; ct < 2; ++ct)
#pragma unroll
        for (int h = 0; h < 2; ++h)
          kf[ct][h] = *(const short8*)&Ks[buf][(kh * 4 + ct * 2 + (ln >> 3)) * 512
                          + (ln & 7) * 64 + (((h * 4 + quad) ^ (ln & 7))) * 8];
      // V frags: row dt*16+ln, kv chunk kh*4+quad
      short8 vf[4];
#pragma unroll
      for (int dt = 0; dt < 4; ++dt)
        vf[dt] = *(const short8*)&Vs[buf][(dt * 4 + (ln >> 2)) * 512 + (ln & 3) * 128
                          + ((((kh * 4 + quad) ^ (ln & 3) ^ (((ln >> 2) & 1) * 4)) & 15)) * 8];

      // S = Q K^T (log2 domain)
      float4v s[2];
#pragma unroll
      for (int ct = 0; ct < 2; ++ct) {
        s[ct] = MFMA16(aQ[0], kf[ct][0], zz);
        s[ct] = MFMA16(aQ[1], kf[ct][1], s[ct]);
      }

      // P = exp2(S); only the last tile needs masking
      if (it == T - 1) {
#pragma unroll
        for (int ct = 0; ct < 2; ++ct)
#pragma unroll
          for (int r = 0; r < 4; ++r) {
            float e = __builtin_amdgcn_exp2f(fminf(s[ct][r], 60.0f));
            if (kv0 + kh * 32 + ct * 16 + ln > qb + qh * 16 + quad * 4 + r) e = 0.f;
            s[ct][r] = e;
          }
      } else {
#pragma unroll
        for (int ct = 0; ct < 2; ++ct)
#pragma unroll
          for (int r = 0; r < 4; ++r)
            s[ct][r] = __builtin_amdgcn_exp2f(fminf(s[ct][r], 60.0f));
      }
#pragma unroll
      for (int r = 0; r < 4; ++r) lp[r] += s[0][r] + s[1][r];

      // P: C-layout -> row-major per-wave LDS -> A-frag
#pragma unroll
      for (int ct = 0; ct < 2; ++ct)
#pragma unroll
        for (int r = 0; r < 4; ++r)
          pw[(quad * 4 + r) * 34 + ct * 16 + ln] = s[ct][r];
      asm volatile("s_waitcnt lgkmcnt(0)" ::: "memory");
      const float4v lo = *(const float4v*)&pw[ln * 34 + quad * 8];
      const float4v hi = *(const float4v*)&pw[ln * 34 + quad * 8 + 4];
      const short8 aP = cvt8(lo, hi);
#pragma unroll
      for (int dt = 0; dt < 4; ++dt)
        o[dt] = MFMA16(aP, vf[dt], o[dt]);
    }
    __syncthreads();  // all compute done; no DMA in flight

    // l: reduce over the 16 col-lanes; O partials into the (free) K/V LDS
#pragma unroll
    for (int r = 0; r < 4; ++r) {
      float lr = lp[r];
      lr += __shfl_xor(lr, 1);
      lr += __shfl_xor(lr, 2);
      lr += __shfl_xor(lr, 4);
      lr += __shfl_xor(lr, 8);
      if (ln == 0) llds[w][quad * 4 + r] = lr;
    }
    float* ow = (float*)&Ks[0][0];  // 32 KB: [kh][32 rows][64 cols]
#pragma unroll
    for (int dt = 0; dt < 4; ++dt)
#pragma unroll
      for (int r = 0; r < 4; ++r)
        ow[kh * 2048 + (qh * 16 + quad * 4 + r) * 64 + dt * 16 + ln] = o[dt][r];
    __syncthreads();

    // combine the 4 kv-quarter partials; coalesced store
#pragma unroll
    for (int jj = 0; jj < 4; ++jj) {
      const int idx = tid + jj * 512;            // 2048 = 32 rows x 64 cols
      const int row = idx >> 6, col = idx & 63;
      float sum = 0.f, lt = 0.f;
#pragma unroll
      for (int k4 = 0; k4 < 4; ++k4) {
        sum += ow[k4 * 2048 + idx];
        lt  += llds[(row >> 4) + 2 * k4][row & 15];
      }
      out[(size_t)(qg0 + row) * DD + col] = sum * __builtin_amdgcn_rcpf(lt);
    }
    __syncthreads();  // guard: next phase's KVSTAGE reuses Ks/Vs
  }
#undef KVSTAGE
}

extern "C" void kernel_launch(void* const* d_in, const int* in_sizes, int n_in,
                              void* d_out, int out_size, void* d_ws, size_t ws_size,
                              hipStream_t stream) {
  const float* x  = (const float*)d_in[0];
  const float* Wq = (const float*)d_in[1];
  const float* Wk = (const float*)d_in[2];
  const float* Wv = (const float*)d_in[3];

  short* Qb  = (short*)d_ws;                       // 2 MB
  short* Kb  = Qb + (size_t)NROWS * DD;            // 2 MB
  short* Vt  = Kb + (size_t)NROWS * DD;            // 2 MB  [b][d][s]
  short* Wb2 = Vt + (size_t)NROWS * DD;            // 384 KB panels

  wcvt_kernel<<<dim3(96), dim3(256), 0, stream>>>(Wq, Wk, Wv, Wb2);
  qkv_kernel<<<dim3(NROWS / 32), dim3(256), 0, stream>>>(x, Wb2, Qb, Kb, Vt);
  attn_kernel<<<dim3(NBATCH * 64), dim3(512), 0, stream>>>(Qb, Kb, Vt, (float*)d_out);
}

// Round 12
// 164.601 us; speedup vs baseline: 1.0049x; 1.0049x over previous
//
#include <hip/hip_runtime.h>
#include <hip/hip_bf16.h>
#include <stdint.h>

typedef __attribute__((ext_vector_type(8))) short  short8;   // 8 bf16 (4 VGPR) MFMA A/B frag
typedef __attribute__((ext_vector_type(4))) short  short4v;
typedef __attribute__((ext_vector_type(4))) float  float4v;  // MFMA C/D frag

#define MFMA16(a, b, c) __builtin_amdgcn_mfma_f32_16x16x32_bf16((a), (b), (c), 0, 0, 0)

#define S_LEN  4096
#define NBATCH 4
#define EMB    1024
#define DD     64
#define NROWS  (NBATCH * S_LEN)  // 16384
#define SCL2   0.1803368801111204f  // (1/sqrt(64)) * log2(e), folded into Wq at wcvt

#define AS1 const __attribute__((address_space(1))) unsigned int*
#define AS3 __attribute__((address_space(3))) unsigned int*

static __device__ __forceinline__ short f2bf(float f) {
  uint32_t u = __float_as_uint(f);
  return (short)((u + 0x7FFFu + ((u >> 16) & 1u)) >> 16);
}
static __device__ __forceinline__ unsigned pk2(float a, float b) {
  union { __hip_bfloat162 h; unsigned u; } z;
  z.h = __float22bfloat162_rn(make_float2(a, b));
  return z.u;
}
static __device__ __forceinline__ short8 cvt8(float4v a, float4v b) {
  union { unsigned u[4]; short8 s; } z;
  z.u[0] = pk2(a[0], a[1]); z.u[1] = pk2(a[2], a[3]);
  z.u[2] = pk2(b[0], b[1]); z.u[3] = pk2(b[2], b[3]);
  return z.s;
}

// ============ Kernel 0: W fp32 -> bf16, reordered into 32-k panels ============
__global__ void wcvt_kernel(const float* __restrict__ Wq, const float* __restrict__ Wk,
                            const float* __restrict__ Wv, short* __restrict__ Wb2) {
  const int t   = blockIdx.x * 256 + threadIdx.x;
  const int row = t >> 7;
  const int k   = (t & 127) * 8;
  const float* src = (row < 64) ? (Wq + (size_t)row * EMB)
                   : (row < 128) ? (Wk + (size_t)(row - 64) * EMB)
                                 : (Wv + (size_t)(row - 128) * EMB);
  const float sc = (row < 64) ? SCL2 : 1.0f;
  float4v a = *(const float4v*)(src + k);
  float4v b = *(const float4v*)(src + k + 4);
#pragma unroll
  for (int i = 0; i < 4; ++i) { a[i] *= sc; b[i] *= sc; }
  *(short8*)(Wb2 + (((k >> 5) * 192 + row) << 5) + (k & 31)) = cvt8(a, b);
}

// ======================= Kernel 1: QKV projection GEMM =======================
// (unchanged -- m97 barrier double-buffer, working)
__global__ __launch_bounds__(256, 2) void qkv_kernel(
    const float* __restrict__ x, const short* __restrict__ Wb2,
    short* __restrict__ Qb, short* __restrict__ Kb, short* __restrict__ Vt) {
  __shared__ float As[2][2048];
  __shared__ short Bs[2][12288];

  const int tid  = threadIdx.x;
  const int w    = tid >> 6;
  const int lane = tid & 63;
  const int ln   = lane & 15;
  const int quad = lane >> 4;
  const int m0   = blockIdx.x * 32;
  const int wr   = w & 1;
  const int wc   = w >> 1;

  const int tA0 = 2 * w, tA1 = 2 * w + 1;
  const float* xA0 = x + (size_t)(m0 + ((tA0 >> 2) << 4) + (lane >> 2)) * EMB
                       + ((tA0 & 3) * 4 + (lane & 3)) * 4;
  const float* xA1 = x + (size_t)(m0 + ((tA1 >> 2) << 4) + (lane >> 2)) * EMB
                       + ((tA1 & 3) * 4 + (lane & 3)) * 4;
  const short* wB = Wb2 + (size_t)(6 * w) * 512 + lane * 8;

#define STAGE(S, BUF) do {                                                      \
    __builtin_amdgcn_global_load_lds((AS1)(xA0 + (S) * 64),                     \
        (AS3)&As[BUF][tA0 * 256], 16, 0, 0);                                    \
    __builtin_amdgcn_global_load_lds((AS1)(xA1 + (S) * 64),                     \
        (AS3)&As[BUF][tA1 * 256], 16, 0, 0);                                    \
    _Pragma("unroll")                                                           \
    for (int j = 0; j < 6; ++j)                                                 \
      __builtin_amdgcn_global_load_lds((AS1)(wB + (size_t)(S) * 12288 + j * 512),\
          (AS3)&Bs[BUF][(6 * w + j) * 512], 16, 0, 0);                          \
  } while (0)

  const float4v zz = {0.f, 0.f, 0.f, 0.f};
  float4v acc[6] = {zz, zz, zz, zz, zz, zz};

  STAGE(0, 0);
  int buf = 0;
  for (int s = 0; s < 16; ++s) {
    __syncthreads();
    if (s + 1 < 16) STAGE(s + 1, buf ^ 1);
    short8 aF[2];
#pragma unroll
    for (int h = 0; h < 2; ++h) {
      const int ai = (wr * 4 + 2 * h + (quad >> 1)) * 256 + (ln * 4 + (quad & 1) * 2) * 4;
      const float4v lo = *(const float4v*)&As[buf][ai];
      const float4v hi = *(const float4v*)&As[buf][ai + 4];
      aF[h] = cvt8(lo, hi);
    }
#pragma unroll
    for (int f = 0; f < 6; ++f) {
      const int cf = wc * 6 + f;
      const short8 b0 = *(const short8*)&Bs[buf][(cf * 16 + ln) * 32 + quad * 8];
      const short8 b1 = *(const short8*)&Bs[buf][6144 + (cf * 16 + ln) * 32 + quad * 8];
      if (wc == 0 || f < 2) {
        acc[f] = MFMA16(aF[0], b0, acc[f]);
        acc[f] = MFMA16(aF[1], b1, acc[f]);
      } else {
        acc[f] = MFMA16(b0, aF[0], acc[f]);
        acc[f] = MFMA16(b1, aF[1], acc[f]);
      }
    }
    buf ^= 1;
  }
#undef STAGE

  const int b  = m0 >> 12;
  const int sb = m0 & (S_LEN - 1);
  if (wc == 0) {
#pragma unroll
    for (int f = 0; f < 6; ++f)
#pragma unroll
      for (int r = 0; r < 4; ++r) {
        const int row = m0 + wr * 16 + quad * 4 + r;
        if (f < 4) Qb[(size_t)row * DD + f * 16 + ln] = f2bf(acc[f][r]);
        else       Kb[(size_t)row * DD + (f - 4) * 16 + ln] = f2bf(acc[f][r]);
      }
  } else {
#pragma unroll
    for (int f = 0; f < 2; ++f)
#pragma unroll
      for (int r = 0; r < 4; ++r) {
        const int row = m0 + wr * 16 + quad * 4 + r;
        Kb[(size_t)row * DD + 32 + f * 16 + ln] = f2bf(acc[f][r]);
      }
#pragma unroll
    for (int f = 2; f < 6; ++f)
#pragma unroll
      for (int r = 0; r < 4; ++r) {
        const int d = (f - 2) * 16 + quad * 4 + r;
        Vt[((size_t)b * DD + d) * S_LEN + sb + wr * 16 + ln] = f2bf(acc[f][r]);
      }
  }
}

// ======================= Kernel 2: causal flash attention =======================
// Round 12: r7 loop shape (direct global K/V register loads, NO in-loop
// barriers) at 2x the TLP: 256 blocks x 1024 thr (16 waves = 4/SIMD; the
// latency-bound fix). Block = 32-row band pair (j,127-j); waves round-robin
// kv-32 tiles (129/pair -> uniform ~8.1 iters/wave). kv-32 keeps live VGPRs
// ~110 (<=128 REQUIRED: a 16-wave block needs 4 waves/SIMD to fit).
// P (fp32, per-wave region) unioned into the O-combine buffer: 130 KB LDS.
__global__ __launch_bounds__(1024, 4) void attn_kernel(
    const short* __restrict__ Qb, const short* __restrict__ Kb,
    const short* __restrict__ Vt, float* __restrict__ out) {
  __shared__ float Obuf[16][2048];  // 128 KB. Wave w region: P [32][36] in loop, O [32][64] after
  __shared__ float llds[16][32];    // 2 KB

  const int tid  = threadIdx.x;
  const int w    = tid >> 6;
  const int lane = tid & 63;
  const int ln   = lane & 15;
  const int quad = lane >> 4;
  const int g    = blockIdx.x;
  const int b    = g & 3;   // with %8 XCD dispatch: XCD x sees batch x&3 -> KV L2-local
  const int j    = g >> 2;  // 0..63 -> band pair (j, 127-j)

  const short* Kbase = Kb + (size_t)b * S_LEN * DD;
  const short* Vbase = Vt + (size_t)b * DD * S_LEN;
  float* pw = &Obuf[w][0];
  const float4v zz = {0.f, 0.f, 0.f, 0.f};

  for (int ph = 0; ph < 2; ++ph) {
    const int band = ph ? (127 - j) : j;
    const int qb   = band * 32;
    const int qg0  = b * S_LEN + qb;
    const int T    = band + 1;  // kv-32 tiles

    short8 aQ[2][2];
#pragma unroll
    for (int rfi = 0; rfi < 2; ++rfi)
#pragma unroll
      for (int h = 0; h < 2; ++h)
        aQ[rfi][h] = *(const short8*)(Qb + (size_t)(qg0 + rfi * 16 + ln) * DD + h * 32 + quad * 8);

    float4v o[2][4];
    float lp[2][4];
#pragma unroll
    for (int rfi = 0; rfi < 2; ++rfi)
#pragma unroll
      for (int d = 0; d < 4; ++d) { o[rfi][d] = zz; lp[rfi][d] = 0.f; }

    for (int it = w; it < T; it += 16) {
      const int kv0 = it * 32;
      // K frags (32 kv x 64 d) and V frags (64 d x 32 kv) straight from L2
      short8 kf[2][2];
#pragma unroll
      for (int ct = 0; ct < 2; ++ct)
#pragma unroll
        for (int h = 0; h < 2; ++h)
          kf[ct][h] = *(const short8*)(Kbase + (size_t)(kv0 + ct * 16 + ln) * DD + h * 32 + quad * 8);
      short8 vf[4];
#pragma unroll
      for (int dt = 0; dt < 4; ++dt)
        vf[dt] = *(const short8*)(Vbase + (size_t)(dt * 16 + ln) * S_LEN + kv0 + quad * 8);

      // S = Q K^T (log2 domain)
      float4v s[2][2];
#pragma unroll
      for (int rfi = 0; rfi < 2; ++rfi)
#pragma unroll
        for (int ct = 0; ct < 2; ++ct) {
          s[rfi][ct] = MFMA16(aQ[rfi][0], kf[ct][0], zz);
          s[rfi][ct] = MFMA16(aQ[rfi][1], kf[ct][1], s[rfi][ct]);
        }

      // P = exp2(S); only the diagonal tile (it == band) masks
      if (it == band) {
#pragma unroll
        for (int rfi = 0; rfi < 2; ++rfi)
#pragma unroll
          for (int ct = 0; ct < 2; ++ct)
#pragma unroll
            for (int r = 0; r < 4; ++r) {
              float e = __builtin_amdgcn_exp2f(fminf(s[rfi][ct][r], 60.0f));
              if (kv0 + ct * 16 + ln > qb + rfi * 16 + quad * 4 + r) e = 0.f;
              s[rfi][ct][r] = e;
            }
      } else {
#pragma unroll
        for (int rfi = 0; rfi < 2; ++rfi)
#pragma unroll
          for (int ct = 0; ct < 2; ++ct)
#pragma unroll
            for (int r = 0; r < 4; ++r)
              s[rfi][ct][r] = __builtin_amdgcn_exp2f(fminf(s[rfi][ct][r], 60.0f));
      }
#pragma unroll
      for (int rfi = 0; rfi < 2; ++rfi)
#pragma unroll
        for (int r = 0; r < 4; ++r)
          lp[rfi][r] += s[rfi][0][r] + s[rfi][1][r];

      // P: C-layout -> row-major LDS [32][36] fp32 -> A-frags (2-way banks both ways)
#pragma unroll
      for (int rfi = 0; rfi < 2; ++rfi)
#pragma unroll
        for (int ct = 0; ct < 2; ++ct)
#pragma unroll
          for (int r = 0; r < 4; ++r)
            pw[(rfi * 16 + quad * 4 + r) * 36 + ct * 16 + ln] = s[rfi][ct][r];
      asm volatile("s_waitcnt lgkmcnt(0)" ::: "memory");
      short8 aP[2];
#pragma unroll
      for (int rfi = 0; rfi < 2; ++rfi) {
        const float4v lo = *(const float4v*)&pw[(rfi * 16 + ln) * 36 + quad * 8];
        const float4v hi = *(const float4v*)&pw[(rfi * 16 + ln) * 36 + quad * 8 + 4];
        aP[rfi] = cvt8(lo, hi);
      }
#pragma unroll
      for (int rfi = 0; rfi < 2; ++rfi)
#pragma unroll
        for (int dt = 0; dt < 4; ++dt)
          o[rfi][dt] = MFMA16(aP[rfi], vf[dt], o[rfi][dt]);
    }

    // epilogue: l shfl-reduce; O partial into this wave's OWN region (P dead)
#pragma unroll
    for (int rfi = 0; rfi < 2; ++rfi)
#pragma unroll
      for (int r = 0; r < 4; ++r) {
        float lr = lp[rfi][r];
        lr += __shfl_xor(lr, 1);
        lr += __shfl_xor(lr, 2);
        lr += __shfl_xor(lr, 4);
        lr += __shfl_xor(lr, 8);
        if (ln == 0) llds[w][rfi * 16 + quad * 4 + r] = lr;
#pragma unroll
        for (int dt = 0; dt < 4; ++dt)
          Obuf[w][(rfi * 16 + quad * 4 + r) * 64 + dt * 16 + ln] = o[rfi][dt][r];
      }
    __syncthreads();

    // combine 16 wave partials; coalesced store (32 rows x 64 cols = 2048)
#pragma unroll
    for (int jj = 0; jj < 2; ++jj) {
      const int idx = tid + jj * 1024;
      const int row = idx >> 6, col = idx & 63;
      float sum = 0.f, lt = 0.f;
#pragma unroll
      for (int wi = 0; wi < 16; ++wi) {
        sum += Obuf[wi][idx];
        lt  += llds[wi][row];
      }
      out[(size_t)(qg0 + row) * DD + col] = sum * __builtin_amdgcn_rcpf(lt);
    }
    __syncthreads();  // regions reused as P in next phase
  }
}

extern "C" void kernel_launch(void* const* d_in, const int* in_sizes, int n_in,
                              void* d_out, int out_size, void* d_ws, size_t ws_size,
                              hipStream_t stream) {
  const float* x  = (const float*)d_in[0];
  const float* Wq = (const float*)d_in[1];
  const float* Wk = (const float*)d_in[2];
  const float* Wv = (const float*)d_in[3];

  short* Qb  = (short*)d_ws;                       // 2 MB
  short* Kb  = Qb + (size_t)NROWS * DD;            // 2 MB
  short* Vt  = Kb + (size_t)NROWS * DD;            // 2 MB  [b][d][s]
  short* Wb2 = Vt + (size_t)NROWS * DD;            // 384 KB panels

  wcvt_kernel<<<dim3(96), dim3(256), 0, stream>>>(Wq, Wk, Wv, Wb2);
  qkv_kernel<<<dim3(NROWS / 32), dim3(256), 0, stream>>>(x, Wb2, Qb, Kb, Vt);
  attn_kernel<<<dim3(NBATCH * 64), dim3(1024), 0, stream>>>(Qb, Kb, Vt, (float*)d_out);
}